// Round 9
// baseline (689.742 us; speedup 1.0000x reference)
//
#include <hip/hip_runtime.h>

typedef short s16x8 __attribute__((ext_vector_type(8)));
typedef float f32x4 __attribute__((ext_vector_type(4)));
typedef float f32x16 __attribute__((ext_vector_type(16)));
typedef unsigned uint2v __attribute__((ext_vector_type(2)));
typedef unsigned short ushort_t;

#define CSC 0.18033688011112042f   // 0.125 * log2(e): softmax scale folded into exp2 domain

// fp32 -> bf16 round-to-nearest-even (finite inputs)
__device__ __forceinline__ ushort_t f2b(float f) {
    union { float f; unsigned int u; } c; c.f = f;
    unsigned int u = c.u;
    return (ushort_t)((u + 0x7fffu + ((u >> 16) & 1u)) >> 16);
}

__device__ __forceinline__ unsigned cvt_pk_bf16(float lo, float hi) {
    unsigned r;
    asm("v_cvt_pk_bf16_f32 %0, %1, %2" : "=v"(r) : "v"(lo), "v"(hi));
    return r;
}

__device__ __forceinline__ float asf(unsigned u) { union { unsigned u; float f; } c; c.u = u; return c.f; }
__device__ __forceinline__ unsigned asu(float f) { union { float f; unsigned u; } c; c.f = f; return c.u; }

// swaps a.hi-lanes with b.lo-lanes; for v=v: {x,y} = {own,partner(lane^32)} on every lane
__device__ __forceinline__ uint2v pl32swap(unsigned a, unsigned b) {
#if __has_builtin(__builtin_amdgcn_permlane32_swap)
    return __builtin_amdgcn_permlane32_swap(a, b, false, false);
#else
    asm volatile("v_permlane32_swap_b32 %0, %1" : "+v"(a), "+v"(b));
    uint2v r; r.x = a; r.y = b; return r;
#endif
}

__device__ __forceinline__ void gload_lds16(const void* g, void* lds) {
    __builtin_amdgcn_global_load_lds(
        (const __attribute__((address_space(1))) unsigned int*)g,
        (__attribute__((address_space(3))) unsigned int*)lds, 16, 0, 0);
}

// ---------------- fp32 -> bf16 conversion ----------------
__global__ __launch_bounds__(256) void cvt_kernel(const float* __restrict__ src,
                                                  ushort_t* __restrict__ dst, int n) {
    int i = (blockIdx.x * 256 + threadIdx.x) * 4;
    if (i >= n) return;
    float4 v = *(const float4*)&src[i];
    ushort4 o = make_ushort4(f2b(v.x), f2b(v.y), f2b(v.z), f2b(v.w));
    *(ushort4*)&dst[i] = o;
}

// all four weight matrices in one launch (grid.y selects)
__global__ __launch_bounds__(256) void cvt4_kernel(const float* __restrict__ W0,
                                                   const float* __restrict__ W1,
                                                   const float* __restrict__ W2,
                                                   const float* __restrict__ W3,
                                                   ushort_t* __restrict__ D0,
                                                   ushort_t* __restrict__ D1,
                                                   ushort_t* __restrict__ D2,
                                                   ushort_t* __restrict__ D3) {
    const int w = blockIdx.y;
    const float* src = (w == 0) ? W0 : (w == 1) ? W1 : (w == 2) ? W2 : W3;
    ushort_t* dst = (w == 0) ? D0 : (w == 1) ? D1 : (w == 2) ? D2 : D3;
    int i = (blockIdx.x * 256 + threadIdx.x) * 4;
    float4 v = *(const float4*)&src[i];
    ushort4 o = make_ushort4(f2b(v.x), f2b(v.y), f2b(v.z), f2b(v.w));
    *(ushort4*)&dst[i] = o;
}

// ---------------- GEMM staging: one 128x32 A-tile chunk + B-tile chunk per thread x2 ----------
__device__ __forceinline__ void stage_gemm(const ushort_t* __restrict__ A,
                                           const ushort_t* __restrict__ B,
                                           int row0, int tileN, int K, int kt,
                                           ushort_t* As, ushort_t* Bs, int tid) {
#pragma unroll
    for (int i = 0; i < 2; ++i) {
        int c = i * 256 + tid;             // 512 chunks of 16B per 8KB tile
        int r = c >> 2;                    // row 0..127
        int scc = (c & 3) ^ ((r >> 1) & 3);
        gload_lds16(A + (size_t)(row0 + r) * K + kt + scc * 8, As + c * 8);
        gload_lds16(B + (size_t)(tileN + r) * K + kt + scc * 8, Bs + c * 8);
    }
}

// ---------------- shared GEMM main loop: C[128,128] = A[M,K] * B[N,K]^T ----------------
__device__ __forceinline__ void gemm_mainloop(const ushort_t* __restrict__ A,
                                              const ushort_t* __restrict__ B,
                                              int row0, int tileN, int K,
                                              ushort_t* As, ushort_t* Bs,   // 3 buffers, stride 4096 elems
                                              f32x4 acc[4][4]) {
    const int tid = threadIdx.x;
    const int lane = tid & 63;
    const int wid = tid >> 6;
    const int wrow = wid >> 1, wcol = wid & 1;
    const int nT = K >> 5;

    stage_gemm(A, B, row0, tileN, K, 0, As, Bs, tid);
    stage_gemm(A, B, row0, tileN, K, 32, As + 4096, Bs + 4096, tid);

    int cur = 0, nx2 = 2;
    for (int t = 0; t < nT; ++t) {
        asm volatile("s_waitcnt vmcnt(8)" ::: "memory");
        __builtin_amdgcn_sched_barrier(0);
        __builtin_amdgcn_s_barrier();
        __builtin_amdgcn_sched_barrier(0);

        int tn = (t + 2 < nT) ? t + 2 : nT - 1;
        stage_gemm(A, B, row0, tileN, K, tn * 32, As + nx2 * 4096, Bs + nx2 * 4096, tid);

        const ushort_t* Ab = As + cur * 4096;
        const ushort_t* Bb = Bs + cur * 4096;

        s16x8 af[4], bfr[4];
#pragma unroll
        for (int m = 0; m < 4; ++m) {
            int row = wrow * 64 + m * 16 + (lane & 15);
            af[m] = *(const s16x8*)&Ab[row * 32 + (((lane >> 4) ^ ((row >> 1) & 3)) * 8)];
        }
#pragma unroll
        for (int n = 0; n < 4; ++n) {
            int row = wcol * 64 + n * 16 + (lane & 15);
            bfr[n] = *(const s16x8*)&Bb[row * 32 + (((lane >> 4) ^ ((row >> 1) & 3)) * 8)];
        }
#pragma unroll
        for (int m = 0; m < 4; ++m)
#pragma unroll
            for (int n = 0; n < 4; ++n)
                acc[m][n] = __builtin_amdgcn_mfma_f32_16x16x32_bf16(af[m], bfr[n], acc[m][n], 0, 0, 0);

        cur = (cur == 2) ? 0 : cur + 1;
        nx2 = (nx2 == 2) ? 0 : nx2 + 1;
    }
}

// ---------------- QKV projection ----------------
// Q,K scatter to [B,H,N,64] bf16; V written TRANSPOSED to [B,H,64,N] bf16.
__global__ __launch_bounds__(256) void gemm_qkv(const ushort_t* __restrict__ X,
                                                const ushort_t* __restrict__ Wq,
                                                const ushort_t* __restrict__ Wk,
                                                const ushort_t* __restrict__ Wv,
                                                const float* __restrict__ bq,
                                                const float* __restrict__ bk,
                                                const float* __restrict__ bv,
                                                ushort_t* __restrict__ Qb,
                                                ushort_t* __restrict__ Kb,
                                                ushort_t* __restrict__ VTb) {
    __shared__ ushort_t As[3 * 128 * 32];
    __shared__ ushort_t Bs[3 * 128 * 32];
    const int K = 1024;
    const int lane = threadIdx.x & 63;
    const int wid = threadIdx.x >> 6;
    const int wrow = wid >> 1, wcol = wid & 1;
    const int row0 = blockIdx.x * 128;
    const int wsel = blockIdx.y >> 3;
    const int tileN = (blockIdx.y & 7) * 128;
    const ushort_t* B = (wsel == 0) ? Wq : (wsel == 1 ? Wk : Wv);
    const float* bias = (wsel == 0) ? bq : (wsel == 1 ? bk : bv);

    f32x4 acc[4][4] = {};
    gemm_mainloop(X, B, row0, tileN, K, As, Bs, acc);

    if (wsel == 2) {
#pragma unroll
        for (int m = 0; m < 4; ++m)
#pragma unroll
            for (int n = 0; n < 4; ++n) {
                int grow = row0 + wrow * 64 + m * 16 + (lane >> 4) * 4;
                int gcol = tileN + wcol * 64 + n * 16 + (lane & 15);
                int b = grow >> 11, nn = grow & 2047;
                int h = gcol >> 6, hd = gcol & 63;
                float bi = bias[gcol];
                ushort4 w;
                w.x = f2b(acc[m][n][0] + bi);
                w.y = f2b(acc[m][n][1] + bi);
                w.z = f2b(acc[m][n][2] + bi);
                w.w = f2b(acc[m][n][3] + bi);
                *(ushort4*)&VTb[((size_t)((b * 16 + h) * 64 + hd)) * 2048 + nn] = w;
            }
    } else {
        ushort_t* dst = (wsel == 0) ? Qb : Kb;
#pragma unroll
        for (int m = 0; m < 4; ++m)
#pragma unroll
            for (int n = 0; n < 4; ++n)
#pragma unroll
                for (int r = 0; r < 4; ++r) {
                    int grow = row0 + wrow * 64 + m * 16 + (lane >> 4) * 4 + r;
                    int gcol = tileN + wcol * 64 + n * 16 + (lane & 15);
                    float v = acc[m][n][r] + bias[gcol];
                    int b = grow >> 11, nn = grow & 2047;
                    int h = gcol >> 6, hd = gcol & 63;
                    dst[((size_t)((b * 16 + h) * 2048 + nn)) * 64 + hd] = f2b(v);
                }
    }
}

// ---------------- output projection: fp32 out + bias ----------------
__global__ __launch_bounds__(256) void gemm_out(const ushort_t* __restrict__ A,
                                                const ushort_t* __restrict__ B,
                                                const float* __restrict__ bias,
                                                float* __restrict__ out) {
    __shared__ ushort_t As[3 * 128 * 32];
    __shared__ ushort_t Bs[3 * 128 * 32];
    const int K = 1024;
    const int lane = threadIdx.x & 63;
    const int wid = threadIdx.x >> 6;
    const int wrow = wid >> 1, wcol = wid & 1;
    const int row0 = blockIdx.x * 128;
    const int tileN = blockIdx.y * 128;

    f32x4 acc[4][4] = {};
    gemm_mainloop(A, B, row0, tileN, K, As, Bs, acc);

#pragma unroll
    for (int m = 0; m < 4; ++m)
#pragma unroll
        for (int n = 0; n < 4; ++n)
#pragma unroll
            for (int r = 0; r < 4; ++r) {
                int grow = row0 + wrow * 64 + m * 16 + (lane >> 4) * 4 + r;
                int gcol = tileN + wcol * 64 + n * 16 + (lane & 15);
                out[(size_t)grow * 1024 + gcol] = acc[m][n][r] + bias[gcol];
            }
}

// ---------------- attention staging: K tile + V^T tile, source-side XOR swizzle ----------------
// 512 threads: each thread stages exactly one 16B chunk of K and one of V^T per tile.
__device__ __forceinline__ void stage_tile(const ushort_t* __restrict__ Kg,
                                           const ushort_t* __restrict__ VTg,
                                           ushort_t* KsB, ushort_t* VsB,
                                           int k0, int tid) {
    int r = tid >> 3;                  // row 0..63
    int scc = (tid & 7) ^ (r & 7);     // swizzled 16B-chunk within the row
    gload_lds16(Kg + (size_t)(k0 + r) * 64 + scc * 8, KsB + tid * 8);
    gload_lds16(VTg + (size_t)r * 2048 + k0 + scc * 8, VsB + tid * 8);
}

// ---------------- attn pipelined body (att[2] split-QK) ----------------
// On entry: saC = full scores of tile t; tile t+1 staged (after vmcnt+barrier); buf layout:
//   Kn/Vn hold tile t+1, Vc holds tile t's V, Kf/Vf are free (tile t-1's, protected by barrier).
// Body: vmcnt(0)+barrier; stage tile t+2 into Kf/Vf; QK_kb0(t+1)->saN[0] (overlaps softmax(t));
//       softmax(t) on saC in-place; PV(t) from Vc; QK_kb1(t+1)->saN[1] (latency hides across barrier).
__device__ __forceinline__ void attn_body(const ushort_t* __restrict__ Kg,
                                          const ushort_t* __restrict__ VTg,
                                          ushort_t* Kn, ushort_t* Kf,
                                          ushort_t* Vc, ushort_t* Vf,
                                          int t, int tid, int q31, int hi, int rsw, int wid,
                                          const s16x8* qf, f32x16* saC, f32x16* saN,
                                          f32x16* o, float& m_run, float& l_run,
                                          float (*Al)[32]) {
    asm volatile("s_waitcnt vmcnt(0)" ::: "memory");   // own stage loads done (issued a full body ago)
    __builtin_amdgcn_sched_barrier(0);
    __builtin_amdgcn_s_barrier();                      // => everyone's tile t+1 staged; bodies t-1 done
    __builtin_amdgcn_sched_barrier(0);

    int tn = (t + 2 <= 31) ? t + 2 : 31;               // tail: dup-stage, never read
    stage_tile(Kg, VTg, Kf, Vf, tn * 64, tid);

    // ---- QK kb=0 of tile t+1 (MFMA overlaps the softmax VALU below) ----
    if (t < 31) {
        saN[0] = (f32x16)0.f;
        __builtin_amdgcn_s_setprio(1);
#pragma unroll
        for (int ds = 0; ds < 4; ++ds) {
            s16x8 kfr = *(const s16x8*)&Kn[q31 * 64 + (((2 * ds + hi) ^ rsw) * 8)];
            saN[0] = __builtin_amdgcn_mfma_f32_32x32x16_bf16(kfr, qf[ds], saN[0], 0, 0, 0);
        }
        __builtin_amdgcn_s_setprio(0);
    }

    // ---- row max of tile t (max3-shaped tree + one permlane cross-half exchange) ----
    f32x16 mx;
#pragma unroll
    for (int r = 0; r < 16; ++r) mx[r] = fmaxf(saC[0][r], saC[1][r]);
    float t0 = fmaxf(fmaxf(mx[0], mx[1]), mx[2]);
    float t1 = fmaxf(fmaxf(mx[3], mx[4]), mx[5]);
    float t2 = fmaxf(fmaxf(mx[6], mx[7]), mx[8]);
    float t3 = fmaxf(fmaxf(mx[9], mx[10]), mx[11]);
    float t4 = fmaxf(fmaxf(mx[12], mx[13]), mx[14]);
    float u0 = fmaxf(fmaxf(t0, t1), t2);
    float u1 = fmaxf(fmaxf(t3, t4), mx[15]);
    float tm = fmaxf(u0, u1);
    {
        uint2v w = pl32swap(asu(tm), asu(tm));
        tm = fmaxf(asf(w.x), asf(w.y));   // max(own, partner)
    }

    // ---- defer-max rescale (T13) ----
    if (!__all(tm - m_run <= 40.0f)) {
        float mn = fmaxf(m_run, tm);
        float alpha = exp2f((m_run - mn) * CSC);
        m_run = mn;
        l_run *= alpha;
        Al[wid][q31] = alpha;          // both halves write identical value
        __builtin_amdgcn_sched_barrier(0);
        asm volatile("s_waitcnt lgkmcnt(0)" ::: "memory");
#pragma unroll
        for (int g = 0; g < 4; ++g) {
            f32x4 av = *(const f32x4*)&Al[wid][hi * 4 + g * 8];
#pragma unroll
            for (int j = 0; j < 4; ++j) {
                o[0][g * 4 + j] *= av[j];
                o[1][g * 4 + j] *= av[j];
            }
        }
    }

    // ---- exp (in-place on saC) + sum + pack to PV A-fragments (T12) ----
    const float negmc = -m_run * CSC;
    s16x8 pa[4];
    float rs = 0.f;
#pragma unroll
    for (int kb = 0; kb < 2; ++kb) {
#pragma unroll
        for (int r = 0; r < 16; ++r)
            saC[kb][r] = exp2f(fmaf(saC[kb][r], CSC, negmc));
        float s0 = ((saC[kb][0] + saC[kb][1]) + (saC[kb][2] + saC[kb][3])) +
                   ((saC[kb][4] + saC[kb][5]) + (saC[kb][6] + saC[kb][7]));
        float s1 = ((saC[kb][8] + saC[kb][9]) + (saC[kb][10] + saC[kb][11])) +
                   ((saC[kb][12] + saC[kb][13]) + (saC[kb][14] + saC[kb][15]));
        rs += s0 + s1;
#pragma unroll
        for (int s = 0; s < 2; ++s) {
            unsigned a0 = cvt_pk_bf16(saC[kb][8 * s + 0], saC[kb][8 * s + 1]);
            unsigned b0 = cvt_pk_bf16(saC[kb][8 * s + 4], saC[kb][8 * s + 5]);
            unsigned a1 = cvt_pk_bf16(saC[kb][8 * s + 2], saC[kb][8 * s + 3]);
            unsigned b1 = cvt_pk_bf16(saC[kb][8 * s + 6], saC[kb][8 * s + 7]);
            uint2v w02 = pl32swap(a0, b0);   // -> word0, word2
            uint2v w13 = pl32swap(a1, b1);   // -> word1, word3
            union { unsigned u[4]; s16x8 v; } fr;
            fr.u[0] = w02.x; fr.u[1] = w13.x; fr.u[2] = w02.y; fr.u[3] = w13.y;
            pa[kb * 2 + s] = fr.v;
        }
    }
    {
        uint2v w = pl32swap(asu(rs), asu(rs));
        l_run += asf(w.x) + asf(w.y);     // own + partner
    }

    // ---- PV(t): O[q][d] += P * V from Vc ----
    __builtin_amdgcn_s_setprio(1);
#pragma unroll
    for (int s = 0; s < 4; ++s)
#pragma unroll
        for (int db = 0; db < 2; ++db) {
            s16x8 vfr = *(const s16x8*)&Vc[(db * 32 + q31) * 64 + (((2 * s + hi) ^ rsw) * 8)];
            o[db] = __builtin_amdgcn_mfma_f32_32x32x16_bf16(pa[s], vfr, o[db], 0, 0, 0);
        }
    __builtin_amdgcn_s_setprio(0);

    // ---- QK kb=1 of tile t+1 (issued last; latency hides across the next barrier) ----
    if (t < 31) {
        saN[1] = (f32x16)0.f;
        __builtin_amdgcn_s_setprio(1);
#pragma unroll
        for (int ds = 0; ds < 4; ++ds) {
            s16x8 kfr = *(const s16x8*)&Kn[(32 + q31) * 64 + (((2 * ds + hi) ^ rsw) * 8)];
            saN[1] = __builtin_amdgcn_mfma_f32_32x32x16_bf16(kfr, qf[ds], saN[1], 0, 0, 0);
        }
        __builtin_amdgcn_s_setprio(0);
    }
}

// ---------------- flash attention fwd (swapped-QK^T 32x32, in-register softmax, att[2]) ----------
// grid: 512 flat blocks of 512 threads (8 waves), XCD-chunked: xcd=fid&7 owns bh in [8*xcd,8*xcd+8).
// Each wave owns 32 q-rows; block covers 256 q-rows; 2 blocks/CU resident in ONE generation
// => 4 waves/SIMD. KVBLK=64; 3 LDS buffers; cross-tile pipeline: QK(t+1) overlaps softmax(t).
__global__ __launch_bounds__(512, 4) void attn_kernel(const ushort_t* __restrict__ Qb,
                                                      const ushort_t* __restrict__ Kb,
                                                      const ushort_t* __restrict__ VTb,
                                                      ushort_t* __restrict__ Ob) {
    const int fid = blockIdx.x;
    const int xcd = fid & 7;
    const int slot = fid >> 3;                 // 0..63
    const int qtile = slot & 7;                // 8 q-tiles of 256 rows
    const int bh = (xcd << 3) + (slot >> 3);   // per-XCD K/V working set ~4MB (L2-fit)
    const int q0 = qtile * 256;
    const int tid = threadIdx.x;
    const int lane = tid & 63;
    const int wid = tid >> 6;                  // 0..7
    const int q31 = lane & 31;
    const int hi = lane >> 5;
    const int rsw = q31 & 7;
    const int b = bh >> 4, h = bh & 15;

    const ushort_t* Q = Qb + (size_t)bh * 2048 * 64;
    const ushort_t* K = Kb + (size_t)bh * 2048 * 64;
    const ushort_t* VT = VTb + (size_t)bh * 64 * 2048;

    __shared__ ushort_t Ksh[3][64 * 64];   // K tile [k][d], chunk-swizzled content
    __shared__ ushort_t Vsh[3][64 * 64];   // V^T tile [d][k], chunk-swizzled content
    __shared__ float Al[8][32];            // per-wave alpha / inv-l redistribution

    const int qw = q0 + wid * 32;

    // Q B-fragments (col=q=lane&31, k-rows d = ds*16 + hi*8 + j) — resident all loop
    s16x8 qf[4];
#pragma unroll
    for (int ds = 0; ds < 4; ++ds)
        qf[ds] = *(const s16x8*)&Q[(size_t)(qw + q31) * 64 + ds * 16 + hi * 8];

    f32x16 o[2] = {};          // O[q-rows][d = db*32 + q31]
    float m_run = -1e30f, l_run = 0.f;

    // prologue: stage tiles 0,1; drain; barrier; compute full QK(0) -> saA
    stage_tile(K, VT, Ksh[0], Vsh[0], 0, tid);
    stage_tile(K, VT, Ksh[1], Vsh[1], 64, tid);
    asm volatile("s_waitcnt vmcnt(0)" ::: "memory");
    __builtin_amdgcn_sched_barrier(0);
    __builtin_amdgcn_s_barrier();
    __builtin_amdgcn_sched_barrier(0);

    f32x16 saA[2], saB[2];
    saA[0] = (f32x16)0.f; saA[1] = (f32x16)0.f;
    __builtin_amdgcn_s_setprio(1);
#pragma unroll
    for (int kb = 0; kb < 2; ++kb)
#pragma unroll
        for (int ds = 0; ds < 4; ++ds) {
            s16x8 kfr = *(const s16x8*)&Ksh[0][(kb * 32 + q31) * 64 + (((2 * ds + hi) ^ rsw) * 8)];
            saA[kb] = __builtin_amdgcn_mfma_f32_32x32x16_bf16(kfr, qf[ds], saA[kb], 0, 0, 0);
        }
    __builtin_amdgcn_s_setprio(0);

    // rotating buffer pointers: Kn/Vn = tile t+1, Vc = tile t's V, Kf/Vf = stage target (t+2)
    ushort_t *Kc = Ksh[0], *Kn = Ksh[1], *Kf = Ksh[2];
    ushort_t *Vc = Vsh[0], *Vn = Vsh[1], *Vf = Vsh[2];

    for (int t = 0; t < 32; t += 2) {
        attn_body(K, VT, Kn, Kf, Vc, Vf, t, tid, q31, hi, rsw, wid,
                  qf, saA, saB, o, m_run, l_run, Al);
        { ushort_t* x = Kc; Kc = Kn; Kn = Kf; Kf = x;
          ushort_t* y = Vc; Vc = Vn; Vn = Vf; Vf = y; }
        attn_body(K, VT, Kn, Kf, Vc, Vf, t + 1, tid, q31, hi, rsw, wid,
                  qf, saB, saA, o, m_run, l_run, Al);
        { ushort_t* x = Kc; Kc = Kn; Kn = Kf; Kf = x;
          ushort_t* y = Vc; Vc = Vn; Vn = Vf; Vf = y; }
    }

    // drain outstanding tail DMA before epilogue (LDS dealloc safety)
    asm volatile("s_waitcnt vmcnt(0)" ::: "memory");

    // ---- epilogue: redistribute 1/l to C-layout rows, normalize, store bf16 ----
    Al[wid][q31] = 1.0f / l_run;     // per-wave row: no cross-wave hazard
    __builtin_amdgcn_sched_barrier(0);
    asm volatile("s_waitcnt lgkmcnt(0)" ::: "memory");
#pragma unroll
    for (int g = 0; g < 4; ++g) {
        f32x4 iv = *(const f32x4*)&Al[wid][hi * 4 + g * 8];
#pragma unroll
        for (int j = 0; j < 4; ++j) {
            int qrow = qw + hi * 4 + g * 8 + j;
            size_t base = ((size_t)(b * 2048 + qrow)) * 1024 + h * 64 + q31;
#pragma unroll
            for (int db = 0; db < 2; ++db)
                Ob[base + db * 32] = f2b(o[db][g * 4 + j] * iv[j]);
        }
    }
}

// ---------------- launcher ----------------
extern "C" void kernel_launch(void* const* d_in, const int* in_sizes, int n_in,
                              void* d_out, int out_size, void* d_ws, size_t ws_size,
                              hipStream_t stream) {
    const float* x  = (const float*)d_in[0];
    const float* Wq = (const float*)d_in[1];
    const float* bq = (const float*)d_in[2];
    const float* Wk = (const float*)d_in[3];
    const float* bk = (const float*)d_in[4];
    const float* Wv = (const float*)d_in[5];
    const float* bv = (const float*)d_in[6];
    const float* Wo = (const float*)d_in[7];
    const float* bo = (const float*)d_in[8];
    float* out = (float*)d_out;

    const size_t XN = (size_t)8192 * 1024;
    const size_t WN = (size_t)1024 * 1024;

    ushort_t* Xb  = (ushort_t*)d_ws;
    ushort_t* Wqb = Xb + XN;
    ushort_t* Wkb = Wqb + WN;
    ushort_t* Wvb = Wkb + WN;
    ushort_t* Wob = Wvb + WN;
    ushort_t* Qb  = Wob + WN;
    ushort_t* Kb  = Qb + XN;
    ushort_t* VTb = Kb + XN;   // V transposed: [B,H,64,2048]
    ushort_t* Ob  = VTb + XN;

    cvt_kernel<<<(int)(XN / 4 / 256), 256, 0, stream>>>(x, Xb, (int)XN);
    dim3 gc((int)(WN / 4 / 256), 4);
    cvt4_kernel<<<gc, 256, 0, stream>>>(Wq, Wk, Wv, Wo, Wqb, Wkb, Wvb, Wob);

    dim3 g1(64, 24);
    gemm_qkv<<<g1, 256, 0, stream>>>(Xb, Wqb, Wkb, Wvb, bq, bk, bv, Qb, Kb, VTb);

    attn_kernel<<<512, 512, 0, stream>>>(Qb, Kb, VTb, Ob);

    dim3 g3(64, 8);
    gemm_out<<<g3, 256, 0, stream>>>(Ob, Wob, bo, out);
}

// Round 10
// 277.974 us; speedup vs baseline: 2.4813x; 2.4813x over previous
//
#include <hip/hip_runtime.h>

typedef short s16x8 __attribute__((ext_vector_type(8)));
typedef float f32x4 __attribute__((ext_vector_type(4)));
typedef float f32x16 __attribute__((ext_vector_type(16)));
typedef unsigned uint2v __attribute__((ext_vector_type(2)));
typedef unsigned short ushort_t;

#define CSC 0.18033688011112042f   // 0.125 * log2(e): softmax scale folded into exp2 domain

// fp32 -> bf16 round-to-nearest-even (finite inputs)
__device__ __forceinline__ ushort_t f2b(float f) {
    union { float f; unsigned int u; } c; c.f = f;
    unsigned int u = c.u;
    return (ushort_t)((u + 0x7fffu + ((u >> 16) & 1u)) >> 16);
}

__device__ __forceinline__ unsigned cvt_pk_bf16(float lo, float hi) {
    unsigned r;
    asm("v_cvt_pk_bf16_f32 %0, %1, %2" : "=v"(r) : "v"(lo), "v"(hi));
    return r;
}

__device__ __forceinline__ float asf(unsigned u) { union { unsigned u; float f; } c; c.u = u; return c.f; }
__device__ __forceinline__ unsigned asu(float f) { union { float f; unsigned u; } c; c.f = f; return c.u; }

// swaps a.hi-lanes with b.lo-lanes; for v=v: {x,y} = {own,partner(lane^32)} on every lane
__device__ __forceinline__ uint2v pl32swap(unsigned a, unsigned b) {
#if __has_builtin(__builtin_amdgcn_permlane32_swap)
    return __builtin_amdgcn_permlane32_swap(a, b, false, false);
#else
    asm volatile("v_permlane32_swap_b32 %0, %1" : "+v"(a), "+v"(b));
    uint2v r; r.x = a; r.y = b; return r;
#endif
}

__device__ __forceinline__ void gload_lds16(const void* g, void* lds) {
    __builtin_amdgcn_global_load_lds(
        (const __attribute__((address_space(1))) unsigned int*)g,
        (__attribute__((address_space(3))) unsigned int*)lds, 16, 0, 0);
}

// ---------------- fp32 -> bf16 conversion ----------------
__global__ __launch_bounds__(256) void cvt_kernel(const float* __restrict__ src,
                                                  ushort_t* __restrict__ dst, int n) {
    int i = (blockIdx.x * 256 + threadIdx.x) * 4;
    if (i >= n) return;
    float4 v = *(const float4*)&src[i];
    ushort4 o = make_ushort4(f2b(v.x), f2b(v.y), f2b(v.z), f2b(v.w));
    *(ushort4*)&dst[i] = o;
}

// all four weight matrices in one launch (grid.y selects)
__global__ __launch_bounds__(256) void cvt4_kernel(const float* __restrict__ W0,
                                                   const float* __restrict__ W1,
                                                   const float* __restrict__ W2,
                                                   const float* __restrict__ W3,
                                                   ushort_t* __restrict__ D0,
                                                   ushort_t* __restrict__ D1,
                                                   ushort_t* __restrict__ D2,
                                                   ushort_t* __restrict__ D3) {
    const int w = blockIdx.y;
    const float* src = (w == 0) ? W0 : (w == 1) ? W1 : (w == 2) ? W2 : W3;
    ushort_t* dst = (w == 0) ? D0 : (w == 1) ? D1 : (w == 2) ? D2 : D3;
    int i = (blockIdx.x * 256 + threadIdx.x) * 4;
    float4 v = *(const float4*)&src[i];
    ushort4 o = make_ushort4(f2b(v.x), f2b(v.y), f2b(v.z), f2b(v.w));
    *(ushort4*)&dst[i] = o;
}

// ---------------- GEMM staging: one 128x32 A-tile chunk + B-tile chunk per thread x2 ----------
__device__ __forceinline__ void stage_gemm(const ushort_t* __restrict__ A,
                                           const ushort_t* __restrict__ B,
                                           int row0, int tileN, int K, int kt,
                                           ushort_t* As, ushort_t* Bs, int tid) {
#pragma unroll
    for (int i = 0; i < 2; ++i) {
        int c = i * 256 + tid;             // 512 chunks of 16B per 8KB tile
        int r = c >> 2;                    // row 0..127
        int scc = (c & 3) ^ ((r >> 1) & 3);
        gload_lds16(A + (size_t)(row0 + r) * K + kt + scc * 8, As + c * 8);
        gload_lds16(B + (size_t)(tileN + r) * K + kt + scc * 8, Bs + c * 8);
    }
}

// ---------------- shared GEMM main loop: C[128,128] = A[M,K] * B[N,K]^T ----------------
__device__ __forceinline__ void gemm_mainloop(const ushort_t* __restrict__ A,
                                              const ushort_t* __restrict__ B,
                                              int row0, int tileN, int K,
                                              ushort_t* As, ushort_t* Bs,   // 3 buffers, stride 4096 elems
                                              f32x4 acc[4][4]) {
    const int tid = threadIdx.x;
    const int lane = tid & 63;
    const int wid = tid >> 6;
    const int wrow = wid >> 1, wcol = wid & 1;
    const int nT = K >> 5;

    stage_gemm(A, B, row0, tileN, K, 0, As, Bs, tid);
    stage_gemm(A, B, row0, tileN, K, 32, As + 4096, Bs + 4096, tid);

    int cur = 0, nx2 = 2;
    for (int t = 0; t < nT; ++t) {
        asm volatile("s_waitcnt vmcnt(8)" ::: "memory");
        __builtin_amdgcn_sched_barrier(0);
        __builtin_amdgcn_s_barrier();
        __builtin_amdgcn_sched_barrier(0);

        int tn = (t + 2 < nT) ? t + 2 : nT - 1;
        stage_gemm(A, B, row0, tileN, K, tn * 32, As + nx2 * 4096, Bs + nx2 * 4096, tid);

        const ushort_t* Ab = As + cur * 4096;
        const ushort_t* Bb = Bs + cur * 4096;

        s16x8 af[4], bfr[4];
#pragma unroll
        for (int m = 0; m < 4; ++m) {
            int row = wrow * 64 + m * 16 + (lane & 15);
            af[m] = *(const s16x8*)&Ab[row * 32 + (((lane >> 4) ^ ((row >> 1) & 3)) * 8)];
        }
#pragma unroll
        for (int n = 0; n < 4; ++n) {
            int row = wcol * 64 + n * 16 + (lane & 15);
            bfr[n] = *(const s16x8*)&Bb[row * 32 + (((lane >> 4) ^ ((row >> 1) & 3)) * 8)];
        }
#pragma unroll
        for (int m = 0; m < 4; ++m)
#pragma unroll
            for (int n = 0; n < 4; ++n)
                acc[m][n] = __builtin_amdgcn_mfma_f32_16x16x32_bf16(af[m], bfr[n], acc[m][n], 0, 0, 0);

        cur = (cur == 2) ? 0 : cur + 1;
        nx2 = (nx2 == 2) ? 0 : nx2 + 1;
    }
}

// ---------------- QKV projection ----------------
// Q,K scatter to [B,H,N,64] bf16; V written TRANSPOSED to [B,H,64,N] bf16.
__global__ __launch_bounds__(256) void gemm_qkv(const ushort_t* __restrict__ X,
                                                const ushort_t* __restrict__ Wq,
                                                const ushort_t* __restrict__ Wk,
                                                const ushort_t* __restrict__ Wv,
                                                const float* __restrict__ bq,
                                                const float* __restrict__ bk,
                                                const float* __restrict__ bv,
                                                ushort_t* __restrict__ Qb,
                                                ushort_t* __restrict__ Kb,
                                                ushort_t* __restrict__ VTb) {
    __shared__ ushort_t As[3 * 128 * 32];
    __shared__ ushort_t Bs[3 * 128 * 32];
    const int K = 1024;
    const int lane = threadIdx.x & 63;
    const int wid = threadIdx.x >> 6;
    const int wrow = wid >> 1, wcol = wid & 1;
    const int row0 = blockIdx.x * 128;
    const int wsel = blockIdx.y >> 3;
    const int tileN = (blockIdx.y & 7) * 128;
    const ushort_t* B = (wsel == 0) ? Wq : (wsel == 1 ? Wk : Wv);
    const float* bias = (wsel == 0) ? bq : (wsel == 1 ? bk : bv);

    f32x4 acc[4][4] = {};
    gemm_mainloop(X, B, row0, tileN, K, As, Bs, acc);

    if (wsel == 2) {
#pragma unroll
        for (int m = 0; m < 4; ++m)
#pragma unroll
            for (int n = 0; n < 4; ++n) {
                int grow = row0 + wrow * 64 + m * 16 + (lane >> 4) * 4;
                int gcol = tileN + wcol * 64 + n * 16 + (lane & 15);
                int b = grow >> 11, nn = grow & 2047;
                int h = gcol >> 6, hd = gcol & 63;
                float bi = bias[gcol];
                ushort4 w;
                w.x = f2b(acc[m][n][0] + bi);
                w.y = f2b(acc[m][n][1] + bi);
                w.z = f2b(acc[m][n][2] + bi);
                w.w = f2b(acc[m][n][3] + bi);
                *(ushort4*)&VTb[((size_t)((b * 16 + h) * 64 + hd)) * 2048 + nn] = w;
            }
    } else {
        ushort_t* dst = (wsel == 0) ? Qb : Kb;
#pragma unroll
        for (int m = 0; m < 4; ++m)
#pragma unroll
            for (int n = 0; n < 4; ++n)
#pragma unroll
                for (int r = 0; r < 4; ++r) {
                    int grow = row0 + wrow * 64 + m * 16 + (lane >> 4) * 4 + r;
                    int gcol = tileN + wcol * 64 + n * 16 + (lane & 15);
                    float v = acc[m][n][r] + bias[gcol];
                    int b = grow >> 11, nn = grow & 2047;
                    int h = gcol >> 6, hd = gcol & 63;
                    dst[((size_t)((b * 16 + h) * 2048 + nn)) * 64 + hd] = f2b(v);
                }
    }
}

// ---------------- output projection: fp32 out + bias ----------------
__global__ __launch_bounds__(256) void gemm_out(const ushort_t* __restrict__ A,
                                                const ushort_t* __restrict__ B,
                                                const float* __restrict__ bias,
                                                float* __restrict__ out) {
    __shared__ ushort_t As[3 * 128 * 32];
    __shared__ ushort_t Bs[3 * 128 * 32];
    const int K = 1024;
    const int lane = threadIdx.x & 63;
    const int wid = threadIdx.x >> 6;
    const int wrow = wid >> 1, wcol = wid & 1;
    const int row0 = blockIdx.x * 128;
    const int tileN = blockIdx.y * 128;

    f32x4 acc[4][4] = {};
    gemm_mainloop(A, B, row0, tileN, K, As, Bs, acc);

#pragma unroll
    for (int m = 0; m < 4; ++m)
#pragma unroll
        for (int n = 0; n < 4; ++n)
#pragma unroll
            for (int r = 0; r < 4; ++r) {
                int grow = row0 + wrow * 64 + m * 16 + (lane >> 4) * 4 + r;
                int gcol = tileN + wcol * 64 + n * 16 + (lane & 15);
                out[(size_t)grow * 1024 + gcol] = acc[m][n][r] + bias[gcol];
            }
}

// ---------------- attention staging: K tile + V^T tile, source-side XOR swizzle ----------------
// 512 threads: each thread stages exactly one 16B chunk of K and one of V^T per tile.
__device__ __forceinline__ void stage_tile(const ushort_t* __restrict__ Kg,
                                           const ushort_t* __restrict__ VTg,
                                           ushort_t* KsB, ushort_t* VsB,
                                           int k0, int tid) {
    int r = tid >> 3;                  // row 0..63
    int scc = (tid & 7) ^ (r & 7);     // swizzled 16B-chunk within the row
    gload_lds16(Kg + (size_t)(k0 + r) * 64 + scc * 8, KsB + tid * 8);
    gload_lds16(VTg + (size_t)r * 2048 + k0 + scc * 8, VsB + tid * 8);
}

// ======== attention body macros — ALL register state in named function-scope vars ========
// (rule #20: no register arrays through function params; straight-line, static indexing)

#define QK_TILE(KB, sa0, sa1)                                                       \
    sa0 = (f32x16)0.f; sa1 = (f32x16)0.f;                                           \
    __builtin_amdgcn_s_setprio(1);                                                  \
    _Pragma("unroll")                                                               \
    for (int ds = 0; ds < 4; ++ds) {                                                \
        s16x8 kf0_ = *(const s16x8*)&(KB)[q31 * 64 + (((2 * ds + hi) ^ rsw) * 8)];  \
        s16x8 kf1_ = *(const s16x8*)&(KB)[(32 + q31) * 64 + (((2 * ds + hi) ^ rsw) * 8)]; \
        sa0 = __builtin_amdgcn_mfma_f32_32x32x16_bf16(kf0_, qf[ds], sa0, 0, 0, 0);  \
        sa1 = __builtin_amdgcn_mfma_f32_32x32x16_bf16(kf1_, qf[ds], sa1, 0, 0, 0);  \
    }                                                                               \
    __builtin_amdgcn_s_setprio(0);

#define PACK8(sav, paL, paH)                                                        \
    {                                                                               \
        unsigned a0_ = cvt_pk_bf16(sav[0], sav[1]);                                 \
        unsigned b0_ = cvt_pk_bf16(sav[4], sav[5]);                                 \
        unsigned a1_ = cvt_pk_bf16(sav[2], sav[3]);                                 \
        unsigned b1_ = cvt_pk_bf16(sav[6], sav[7]);                                 \
        uint2v w02_ = pl32swap(a0_, b0_);                                           \
        uint2v w13_ = pl32swap(a1_, b1_);                                           \
        union { unsigned u[4]; s16x8 v; } frL_;                                     \
        frL_.u[0] = w02_.x; frL_.u[1] = w13_.x; frL_.u[2] = w02_.y; frL_.u[3] = w13_.y; \
        paL = frL_.v;                                                               \
        unsigned a2_ = cvt_pk_bf16(sav[8], sav[9]);                                 \
        unsigned b2_ = cvt_pk_bf16(sav[12], sav[13]);                               \
        unsigned a3_ = cvt_pk_bf16(sav[10], sav[11]);                               \
        unsigned b3_ = cvt_pk_bf16(sav[14], sav[15]);                               \
        uint2v w02h_ = pl32swap(a2_, b2_);                                          \
        uint2v w13h_ = pl32swap(a3_, b3_);                                          \
        union { unsigned u[4]; s16x8 v; } frH_;                                     \
        frH_.u[0] = w02h_.x; frH_.u[1] = w13h_.x; frH_.u[2] = w02h_.y; frH_.u[3] = w13h_.y; \
        paH = frH_.v;                                                               \
    }

#define SM_BLOCK(sa0, sa1, pa0, pa1, pa2, pa3)                                      \
    {                                                                               \
        f32x16 mx_;                                                                 \
        _Pragma("unroll")                                                           \
        for (int r = 0; r < 16; ++r) mx_[r] = fmaxf(sa0[r], sa1[r]);                \
        float t0_ = fmaxf(fmaxf(mx_[0], mx_[1]), mx_[2]);                           \
        float t1_ = fmaxf(fmaxf(mx_[3], mx_[4]), mx_[5]);                           \
        float t2_ = fmaxf(fmaxf(mx_[6], mx_[7]), mx_[8]);                           \
        float t3_ = fmaxf(fmaxf(mx_[9], mx_[10]), mx_[11]);                         \
        float t4_ = fmaxf(fmaxf(mx_[12], mx_[13]), mx_[14]);                        \
        float tm_ = fmaxf(fmaxf(fmaxf(t0_, t1_), t2_),                              \
                          fmaxf(fmaxf(t3_, t4_), mx_[15]));                         \
        { uint2v w_ = pl32swap(asu(tm_), asu(tm_));                                 \
          tm_ = fmaxf(asf(w_.x), asf(w_.y)); }                                      \
        if (!__all(tm_ - m_run <= 40.0f)) {                                         \
            float mn_ = fmaxf(m_run, tm_);                                          \
            float al_ = exp2f((m_run - mn_) * CSC);                                 \
            m_run = mn_; l_run *= al_;                                              \
            Al[wid][q31] = al_;                                                     \
            __builtin_amdgcn_sched_barrier(0);                                      \
            asm volatile("s_waitcnt lgkmcnt(0)" ::: "memory");                      \
            _Pragma("unroll")                                                       \
            for (int g = 0; g < 4; ++g) {                                           \
                f32x4 av_ = *(const f32x4*)&Al[wid][hi * 4 + g * 8];                \
                _Pragma("unroll")                                                   \
                for (int j = 0; j < 4; ++j) {                                       \
                    o0[g * 4 + j] *= av_[j];                                        \
                    o1[g * 4 + j] *= av_[j];                                        \
                }                                                                   \
            }                                                                       \
        }                                                                           \
        const float negmc_ = -m_run * CSC;                                          \
        _Pragma("unroll")                                                           \
        for (int r = 0; r < 16; ++r) sa0[r] = exp2f(fmaf(sa0[r], CSC, negmc_));     \
        _Pragma("unroll")                                                           \
        for (int r = 0; r < 16; ++r) sa1[r] = exp2f(fmaf(sa1[r], CSC, negmc_));     \
        float rs_ = (((sa0[0] + sa0[1]) + (sa0[2] + sa0[3])) +                      \
                     ((sa0[4] + sa0[5]) + (sa0[6] + sa0[7]))) +                     \
                    (((sa0[8] + sa0[9]) + (sa0[10] + sa0[11])) +                    \
                     ((sa0[12] + sa0[13]) + (sa0[14] + sa0[15])));                  \
        rs_ += (((sa1[0] + sa1[1]) + (sa1[2] + sa1[3])) +                           \
                ((sa1[4] + sa1[5]) + (sa1[6] + sa1[7]))) +                          \
               (((sa1[8] + sa1[9]) + (sa1[10] + sa1[11])) +                         \
                ((sa1[12] + sa1[13]) + (sa1[14] + sa1[15])));                       \
        PACK8(sa0, pa0, pa1);                                                       \
        PACK8(sa1, pa2, pa3);                                                       \
        { uint2v w_ = pl32swap(asu(rs_), asu(rs_));                                 \
          l_run += asf(w_.x) + asf(w_.y); }                                         \
    }

#define PV_BLOCK(pa0, pa1, pa2, pa3, VB)                                            \
    __builtin_amdgcn_s_setprio(1);                                                  \
    {                                                                               \
        s16x8 vf0_, vf1_;                                                           \
        vf0_ = *(const s16x8*)&(VB)[q31 * 64 + ((hi ^ rsw) * 8)];                   \
        vf1_ = *(const s16x8*)&(VB)[(32 + q31) * 64 + ((hi ^ rsw) * 8)];            \
        o0 = __builtin_amdgcn_mfma_f32_32x32x16_bf16(pa0, vf0_, o0, 0, 0, 0);       \
        o1 = __builtin_amdgcn_mfma_f32_32x32x16_bf16(pa0, vf1_, o1, 0, 0, 0);       \
        vf0_ = *(const s16x8*)&(VB)[q31 * 64 + (((2 + hi) ^ rsw) * 8)];             \
        vf1_ = *(const s16x8*)&(VB)[(32 + q31) * 64 + (((2 + hi) ^ rsw) * 8)];      \
        o0 = __builtin_amdgcn_mfma_f32_32x32x16_bf16(pa1, vf0_, o0, 0, 0, 0);       \
        o1 = __builtin_amdgcn_mfma_f32_32x32x16_bf16(pa1, vf1_, o1, 0, 0, 0);       \
        vf0_ = *(const s16x8*)&(VB)[q31 * 64 + (((4 + hi) ^ rsw) * 8)];             \
        vf1_ = *(const s16x8*)&(VB)[(32 + q31) * 64 + (((4 + hi) ^ rsw) * 8)];      \
        o0 = __builtin_amdgcn_mfma_f32_32x32x16_bf16(pa2, vf0_, o0, 0, 0, 0);       \
        o1 = __builtin_amdgcn_mfma_f32_32x32x16_bf16(pa2, vf1_, o1, 0, 0, 0);       \
        vf0_ = *(const s16x8*)&(VB)[q31 * 64 + (((6 + hi) ^ rsw) * 8)];             \
        vf1_ = *(const s16x8*)&(VB)[(32 + q31) * 64 + (((6 + hi) ^ rsw) * 8)];      \
        o0 = __builtin_amdgcn_mfma_f32_32x32x16_bf16(pa3, vf0_, o0, 0, 0, 0);       \
        o1 = __builtin_amdgcn_mfma_f32_32x32x16_bf16(pa3, vf1_, o1, 0, 0, 0);       \
    }                                                                               \
    __builtin_amdgcn_s_setprio(0);

// one interval = two tiles from one buffer set; stage same set for t+4/t+5 at end
#define INTERVAL(KB0, VB0, KB1, VB1, TS0, TS1)                                      \
    asm volatile("s_waitcnt vmcnt(4)" ::: "memory");                                \
    __builtin_amdgcn_sched_barrier(0);                                              \
    __builtin_amdgcn_s_barrier();                                                   \
    __builtin_amdgcn_sched_barrier(0);                                              \
    QK_TILE(KB0, sa_a0, sa_a1);                                                     \
    SM_BLOCK(sa_a0, sa_a1, pa_a0, pa_a1, pa_a2, pa_a3);                             \
    QK_TILE(KB1, sa_b0, sa_b1);                                                     \
    PV_BLOCK(pa_a0, pa_a1, pa_a2, pa_a3, VB0);                                      \
    SM_BLOCK(sa_b0, sa_b1, pa_b0, pa_b1, pa_b2, pa_b3);                             \
    PV_BLOCK(pa_b0, pa_b1, pa_b2, pa_b3, VB1);                                      \
    __builtin_amdgcn_sched_barrier(0);                                              \
    __builtin_amdgcn_s_barrier();                                                   \
    __builtin_amdgcn_sched_barrier(0);                                              \
    stage_tile(K, VT, KB0, VB0, (TS0) * 64, tid);                                   \
    stage_tile(K, VT, KB1, VB1, (TS1) * 64, tid);

// ---------------- flash attention fwd (swapped-QK^T 32x32, in-reg softmax, paired tiles) -------
// grid: 512 flat blocks of 512 threads (8 waves), XCD-chunked. Wave owns 32 q-rows.
// 2 tiles per sync interval from 4 LDS buffer pairs (64KB): QK(t+1) interleaves with SM/PV(t)
// in straight-line code (compiler ILP); 1 vmcnt + 2 barriers per 2 tiles.
__global__ __launch_bounds__(512, 4) void attn_kernel(const ushort_t* __restrict__ Qb,
                                                      const ushort_t* __restrict__ Kb,
                                                      const ushort_t* __restrict__ VTb,
                                                      ushort_t* __restrict__ Ob) {
    const int fid = blockIdx.x;
    const int xcd = fid & 7;
    const int slot = fid >> 3;                 // 0..63
    const int qtile = slot & 7;                // 8 q-tiles of 256 rows
    const int bh = (xcd << 3) + (slot >> 3);   // per-XCD K/V working set ~4MB (L2-fit)
    const int q0 = qtile * 256;
    const int tid = threadIdx.x;
    const int lane = tid & 63;
    const int wid = tid >> 6;                  // 0..7
    const int q31 = lane & 31;
    const int hi = lane >> 5;
    const int rsw = q31 & 7;
    const int b = bh >> 4, h = bh & 15;

    const ushort_t* Q = Qb + (size_t)bh * 2048 * 64;
    const ushort_t* K = Kb + (size_t)bh * 2048 * 64;
    const ushort_t* VT = VTb + (size_t)bh * 64 * 2048;

    __shared__ ushort_t Ksh[4][64 * 64];   // 4 K tile bufs (2 sets of 2), chunk-swizzled
    __shared__ ushort_t Vsh[4][64 * 64];   // 4 V^T tile bufs
    __shared__ float Al[8][32];            // per-wave alpha / inv-l redistribution

    const int qw = q0 + wid * 32;

    // Q B-fragments (col=q=lane&31, k-rows d = ds*16 + hi*8 + j) — resident all loop
    s16x8 qf[4];
#pragma unroll
    for (int ds = 0; ds < 4; ++ds)
        qf[ds] = *(const s16x8*)&Q[(size_t)(qw + q31) * 64 + ds * 16 + hi * 8];

    f32x16 o0 = {}, o1 = {};               // O[q-rows][d = db*32 + q31], db = 0/1
    float m_run = -1e30f, l_run = 0.f;

    // named register state for the paired-tile pipeline (rule #20 safe)
    f32x16 sa_a0, sa_a1, sa_b0, sa_b1;
    s16x8 pa_a0, pa_a1, pa_a2, pa_a3;
    s16x8 pa_b0, pa_b1, pa_b2, pa_b3;

    ushort_t* const KA0 = Ksh[0]; ushort_t* const KA1 = Ksh[1];
    ushort_t* const KB0 = Ksh[2]; ushort_t* const KB1 = Ksh[3];
    ushort_t* const VA0 = Vsh[0]; ushort_t* const VA1 = Vsh[1];
    ushort_t* const VB0_ = Vsh[2]; ushort_t* const VB1_ = Vsh[3];

    // prologue: stage tiles 0,1 (set A) and 2,3 (set B) — 8 loads outstanding
    stage_tile(K, VT, KA0, VA0, 0, tid);
    stage_tile(K, VT, KA1, VA1, 64, tid);
    stage_tile(K, VT, KB0, VB0_, 128, tid);
    stage_tile(K, VT, KB1, VB1_, 192, tid);

    // 16 intervals; interval i handles tiles 2i,2i+1; stages tiles 2i+4,2i+5 (clamped dups at tail)
    for (int p = 0; p < 16; p += 2) {
        {
            int ts0 = 2 * p + 4, ts1 = 2 * p + 5;
            if (ts0 > 31) ts0 = 30;
            if (ts1 > 31) ts1 = 31;
            INTERVAL(KA0, VA0, KA1, VA1, ts0, ts1);
        }
        {
            int ts0 = 2 * p + 6, ts1 = 2 * p + 7;
            if (ts0 > 31) ts0 = 30;
            if (ts1 > 31) ts1 = 31;
            INTERVAL(KB0, VB0_, KB1, VB1_, ts0, ts1);
        }
    }

    // drain outstanding tail DMA before epilogue
    asm volatile("s_waitcnt vmcnt(0)" ::: "memory");

    // ---- epilogue: redistribute 1/l to C-layout rows, normalize, store bf16 ----
    Al[wid][q31] = 1.0f / l_run;     // per-wave row: no cross-wave hazard
    __builtin_amdgcn_sched_barrier(0);
    asm volatile("s_waitcnt lgkmcnt(0)" ::: "memory");
#pragma unroll
    for (int g = 0; g < 4; ++g) {
        f32x4 iv = *(const f32x4*)&Al[wid][hi * 4 + g * 8];
#pragma unroll
        for (int j = 0; j < 4; ++j) {
            int qrow = qw + hi * 4 + g * 8 + j;
            size_t base = ((size_t)(b * 2048 + qrow)) * 1024 + h * 64 + q31;
            Ob[base] = f2b(o0[g * 4 + j] * iv[j]);
            Ob[base + 32] = f2b(o1[g * 4 + j] * iv[j]);
        }
    }
}

// ---------------- launcher ----------------
extern "C" void kernel_launch(void* const* d_in, const int* in_sizes, int n_in,
                              void* d_out, int out_size, void* d_ws, size_t ws_size,
                              hipStream_t stream) {
    const float* x  = (const float*)d_in[0];
    const float* Wq = (const float*)d_in[1];
    const float* bq = (const float*)d_in[2];
    const float* Wk = (const float*)d_in[3];
    const float* bk = (const float*)d_in[4];
    const float* Wv = (const float*)d_in[5];
    const float* bv = (const float*)d_in[6];
    const float* Wo = (const float*)d_in[7];
    const float* bo = (const float*)d_in[8];
    float* out = (float*)d_out;

    const size_t XN = (size_t)8192 * 1024;
    const size_t WN = (size_t)1024 * 1024;

    ushort_t* Xb  = (ushort_t*)d_ws;
    ushort_t* Wqb = Xb + XN;
    ushort_t* Wkb = Wqb + WN;
    ushort_t* Wvb = Wkb + WN;
    ushort_t* Wob = Wvb + WN;
    ushort_t* Qb  = Wob + WN;
    ushort_t* Kb  = Qb + XN;
    ushort_t* VTb = Kb + XN;   // V transposed: [B,H,64,2048]
    ushort_t* Ob  = VTb + XN;

    cvt_kernel<<<(int)(XN / 4 / 256), 256, 0, stream>>>(x, Xb, (int)XN);
    dim3 gc((int)(WN / 4 / 256), 4);
    cvt4_kernel<<<gc, 256, 0, stream>>>(Wq, Wk, Wv, Wo, Wqb, Wkb, Wvb, Wob);

    dim3 g1(64, 24);
    gemm_qkv<<<g1, 256, 0, stream>>>(Xb, Wqb, Wkb, Wvb, bq, bk, bv, Qb, Kb, VTb);

    attn_kernel<<<512, 512, 0, stream>>>(Qb, Kb, VTb, Ob);

    dim3 g3(64, 8);
    gemm_out<<<g3, 256, 0, stream>>>(Ob, Wob, bo, out);
}

// Round 11
// 232.760 us; speedup vs baseline: 2.9633x; 1.1943x over previous
//
#include <hip/hip_runtime.h>

typedef short s16x8 __attribute__((ext_vector_type(8)));
typedef float f32x4 __attribute__((ext_vector_type(4)));
typedef float f32x16 __attribute__((ext_vector_type(16)));
typedef unsigned uint2v __attribute__((ext_vector_type(2)));
typedef unsigned short ushort_t;

#define CSC 0.18033688011112042f   // 0.125 * log2(e): softmax scale folded into exp2 domain
#define MFIX 16.0f                 // fixed softmax shift: exact (shift-invariant); overflow needs s>700

// fp32 -> bf16 round-to-nearest-even (finite inputs)
__device__ __forceinline__ ushort_t f2b(float f) {
    union { float f; unsigned int u; } c; c.f = f;
    unsigned int u = c.u;
    return (ushort_t)((u + 0x7fffu + ((u >> 16) & 1u)) >> 16);
}

__device__ __forceinline__ unsigned cvt_pk_bf16(float lo, float hi) {
    unsigned r;
    asm("v_cvt_pk_bf16_f32 %0, %1, %2" : "=v"(r) : "v"(lo), "v"(hi));
    return r;
}

__device__ __forceinline__ float asf(unsigned u) { union { unsigned u; float f; } c; c.u = u; return c.f; }
__device__ __forceinline__ unsigned asu(float f) { union { float f; unsigned u; } c; c.f = f; return c.u; }

// swaps a.hi-lanes with b.lo-lanes; for v=v: {x,y} = {own,partner(lane^32)} on every lane
__device__ __forceinline__ uint2v pl32swap(unsigned a, unsigned b) {
#if __has_builtin(__builtin_amdgcn_permlane32_swap)
    return __builtin_amdgcn_permlane32_swap(a, b, false, false);
#else
    asm volatile("v_permlane32_swap_b32 %0, %1" : "+v"(a), "+v"(b));
    uint2v r; r.x = a; r.y = b; return r;
#endif
}

__device__ __forceinline__ void gload_lds16(const void* g, void* lds) {
    __builtin_amdgcn_global_load_lds(
        (const __attribute__((address_space(1))) unsigned int*)g,
        (__attribute__((address_space(3))) unsigned int*)lds, 16, 0, 0);
}

// ---------------- fp32 -> bf16 conversion ----------------
__global__ __launch_bounds__(256) void cvt_kernel(const float* __restrict__ src,
                                                  ushort_t* __restrict__ dst, int n) {
    int i = (blockIdx.x * 256 + threadIdx.x) * 4;
    if (i >= n) return;
    float4 v = *(const float4*)&src[i];
    ushort4 o = make_ushort4(f2b(v.x), f2b(v.y), f2b(v.z), f2b(v.w));
    *(ushort4*)&dst[i] = o;
}

// all four weight matrices in one launch (grid.y selects)
__global__ __launch_bounds__(256) void cvt4_kernel(const float* __restrict__ W0,
                                                   const float* __restrict__ W1,
                                                   const float* __restrict__ W2,
                                                   const float* __restrict__ W3,
                                                   ushort_t* __restrict__ D0,
                                                   ushort_t* __restrict__ D1,
                                                   ushort_t* __restrict__ D2,
                                                   ushort_t* __restrict__ D3) {
    const int w = blockIdx.y;
    const float* src = (w == 0) ? W0 : (w == 1) ? W1 : (w == 2) ? W2 : W3;
    ushort_t* dst = (w == 0) ? D0 : (w == 1) ? D1 : (w == 2) ? D2 : D3;
    int i = (blockIdx.x * 256 + threadIdx.x) * 4;
    float4 v = *(const float4*)&src[i];
    ushort4 o = make_ushort4(f2b(v.x), f2b(v.y), f2b(v.z), f2b(v.w));
    *(ushort4*)&dst[i] = o;
}

// ---------------- GEMM staging: one 128x32 A-tile chunk + B-tile chunk per thread x2 ----------
__device__ __forceinline__ void stage_gemm(const ushort_t* __restrict__ A,
                                           const ushort_t* __restrict__ B,
                                           int row0, int tileN, int K, int kt,
                                           ushort_t* As, ushort_t* Bs, int tid) {
#pragma unroll
    for (int i = 0; i < 2; ++i) {
        int c = i * 256 + tid;             // 512 chunks of 16B per 8KB tile
        int r = c >> 2;                    // row 0..127
        int scc = (c & 3) ^ ((r >> 1) & 3);
        gload_lds16(A + (size_t)(row0 + r) * K + kt + scc * 8, As + c * 8);
        gload_lds16(B + (size_t)(tileN + r) * K + kt + scc * 8, Bs + c * 8);
    }
}

// ---------------- shared GEMM main loop: C[128,128] = A[M,K] * B[N,K]^T ----------------
__device__ __forceinline__ void gemm_mainloop(const ushort_t* __restrict__ A,
                                              const ushort_t* __restrict__ B,
                                              int row0, int tileN, int K,
                                              ushort_t* As, ushort_t* Bs,   // 3 buffers, stride 4096 elems
                                              f32x4 acc[4][4]) {
    const int tid = threadIdx.x;
    const int lane = tid & 63;
    const int wid = tid >> 6;
    const int wrow = wid >> 1, wcol = wid & 1;
    const int nT = K >> 5;

    stage_gemm(A, B, row0, tileN, K, 0, As, Bs, tid);
    stage_gemm(A, B, row0, tileN, K, 32, As + 4096, Bs + 4096, tid);

    int cur = 0, nx2 = 2;
    for (int t = 0; t < nT; ++t) {
        asm volatile("s_waitcnt vmcnt(8)" ::: "memory");
        __builtin_amdgcn_sched_barrier(0);
        __builtin_amdgcn_s_barrier();
        __builtin_amdgcn_sched_barrier(0);

        int tn = (t + 2 < nT) ? t + 2 : nT - 1;
        stage_gemm(A, B, row0, tileN, K, tn * 32, As + nx2 * 4096, Bs + nx2 * 4096, tid);

        const ushort_t* Ab = As + cur * 4096;
        const ushort_t* Bb = Bs + cur * 4096;

        s16x8 af[4], bfr[4];
#pragma unroll
        for (int m = 0; m < 4; ++m) {
            int row = wrow * 64 + m * 16 + (lane & 15);
            af[m] = *(const s16x8*)&Ab[row * 32 + (((lane >> 4) ^ ((row >> 1) & 3)) * 8)];
        }
#pragma unroll
        for (int n = 0; n < 4; ++n) {
            int row = wcol * 64 + n * 16 + (lane & 15);
            bfr[n] = *(const s16x8*)&Bb[row * 32 + (((lane >> 4) ^ ((row >> 1) & 3)) * 8)];
        }
#pragma unroll
        for (int m = 0; m < 4; ++m)
#pragma unroll
            for (int n = 0; n < 4; ++n)
                acc[m][n] = __builtin_amdgcn_mfma_f32_16x16x32_bf16(af[m], bfr[n], acc[m][n], 0, 0, 0);

        cur = (cur == 2) ? 0 : cur + 1;
        nx2 = (nx2 == 2) ? 0 : nx2 + 1;
    }
}

// ---------------- QKV projection ----------------
// Q,K scatter to [B,H,N,64] bf16; V written TRANSPOSED to [B,H,64,N] bf16.
__global__ __launch_bounds__(256) void gemm_qkv(const ushort_t* __restrict__ X,
                                                const ushort_t* __restrict__ Wq,
                                                const ushort_t* __restrict__ Wk,
                                                const ushort_t* __restrict__ Wv,
                                                const float* __restrict__ bq,
                                                const float* __restrict__ bk,
                                                const float* __restrict__ bv,
                                                ushort_t* __restrict__ Qb,
                                                ushort_t* __restrict__ Kb,
                                                ushort_t* __restrict__ VTb) {
    __shared__ ushort_t As[3 * 128 * 32];
    __shared__ ushort_t Bs[3 * 128 * 32];
    const int K = 1024;
    const int lane = threadIdx.x & 63;
    const int wid = threadIdx.x >> 6;
    const int wrow = wid >> 1, wcol = wid & 1;
    const int row0 = blockIdx.x * 128;
    const int wsel = blockIdx.y >> 3;
    const int tileN = (blockIdx.y & 7) * 128;
    const ushort_t* B = (wsel == 0) ? Wq : (wsel == 1 ? Wk : Wv);
    const float* bias = (wsel == 0) ? bq : (wsel == 1 ? bk : bv);

    f32x4 acc[4][4] = {};
    gemm_mainloop(X, B, row0, tileN, K, As, Bs, acc);

    if (wsel == 2) {
#pragma unroll
        for (int m = 0; m < 4; ++m)
#pragma unroll
            for (int n = 0; n < 4; ++n) {
                int grow = row0 + wrow * 64 + m * 16 + (lane >> 4) * 4;
                int gcol = tileN + wcol * 64 + n * 16 + (lane & 15);
                int b = grow >> 11, nn = grow & 2047;
                int h = gcol >> 6, hd = gcol & 63;
                float bi = bias[gcol];
                ushort4 w;
                w.x = f2b(acc[m][n][0] + bi);
                w.y = f2b(acc[m][n][1] + bi);
                w.z = f2b(acc[m][n][2] + bi);
                w.w = f2b(acc[m][n][3] + bi);
                *(ushort4*)&VTb[((size_t)((b * 16 + h) * 64 + hd)) * 2048 + nn] = w;
            }
    } else {
        ushort_t* dst = (wsel == 0) ? Qb : Kb;
#pragma unroll
        for (int m = 0; m < 4; ++m)
#pragma unroll
            for (int n = 0; n < 4; ++n)
#pragma unroll
                for (int r = 0; r < 4; ++r) {
                    int grow = row0 + wrow * 64 + m * 16 + (lane >> 4) * 4 + r;
                    int gcol = tileN + wcol * 64 + n * 16 + (lane & 15);
                    float v = acc[m][n][r] + bias[gcol];
                    int b = grow >> 11, nn = grow & 2047;
                    int h = gcol >> 6, hd = gcol & 63;
                    dst[((size_t)((b * 16 + h) * 2048 + nn)) * 64 + hd] = f2b(v);
                }
    }
}

// ---------------- output projection: fp32 out + bias ----------------
__global__ __launch_bounds__(256) void gemm_out(const ushort_t* __restrict__ A,
                                                const ushort_t* __restrict__ B,
                                                const float* __restrict__ bias,
                                                float* __restrict__ out) {
    __shared__ ushort_t As[3 * 128 * 32];
    __shared__ ushort_t Bs[3 * 128 * 32];
    const int K = 1024;
    const int lane = threadIdx.x & 63;
    const int wid = threadIdx.x >> 6;
    const int wrow = wid >> 1, wcol = wid & 1;
    const int row0 = blockIdx.x * 128;
    const int tileN = blockIdx.y * 128;

    f32x4 acc[4][4] = {};
    gemm_mainloop(A, B, row0, tileN, K, As, Bs, acc);

#pragma unroll
    for (int m = 0; m < 4; ++m)
#pragma unroll
        for (int n = 0; n < 4; ++n)
#pragma unroll
            for (int r = 0; r < 4; ++r) {
                int grow = row0 + wrow * 64 + m * 16 + (lane >> 4) * 4 + r;
                int gcol = tileN + wcol * 64 + n * 16 + (lane & 15);
                out[(size_t)grow * 1024 + gcol] = acc[m][n][r] + bias[gcol];
            }
}

// ---------------- attention staging: K tile + V^T tile, source-side XOR swizzle ----------------
// 512 threads: each thread stages exactly one 16B chunk of K and one of V^T per tile.
__device__ __forceinline__ void stage_tile(const ushort_t* __restrict__ Kg,
                                           const ushort_t* __restrict__ VTg,
                                           ushort_t* KsB, ushort_t* VsB,
                                           int k0, int tid) {
    int r = tid >> 3;                  // row 0..63
    int scc = (tid & 7) ^ (r & 7);     // swizzled 16B-chunk within the row
    gload_lds16(Kg + (size_t)(k0 + r) * 64 + scc * 8, KsB + tid * 8);
    gload_lds16(VTg + (size_t)r * 2048 + k0 + scc * 8, VsB + tid * 8);
}

// ---------------- flash attention fwd (swapped-QK^T 32x32, in-register softmax) ----------------
// ROUND-6 STRUCTURE (best measured: 133.6 us) with FIXED-SHIFT softmax: softmax is
// shift-invariant, and exp2((s-16)*CSC) cannot overflow for any |s| < ~700 (scores here are
// N(0,1), max ~6.5) -> drop the online max tree / rescale path entirely (~25% of softmax VALU).
// grid: 512 flat blocks of 512 threads (8 waves), XCD-chunked: xcd=fid&7 owns bh in [8*xcd,8*xcd+8).
// Each wave owns 32 q-rows; block covers 256 q-rows; 2 blocks/CU resident in ONE generation
// => 4 waves/SIMD. KVBLK=64; 3 LDS buffers, 1 barrier/tile, 2-deep DMA.
__global__ __launch_bounds__(512, 4) void attn_kernel(const ushort_t* __restrict__ Qb,
                                                      const ushort_t* __restrict__ Kb,
                                                      const ushort_t* __restrict__ VTb,
                                                      ushort_t* __restrict__ Ob) {
    const int fid = blockIdx.x;
    const int xcd = fid & 7;
    const int slot = fid >> 3;                 // 0..63
    const int qtile = slot & 7;                // 8 q-tiles of 256 rows
    const int bh = (xcd << 3) + (slot >> 3);   // per-XCD K/V working set ~4MB (L2-fit)
    const int q0 = qtile * 256;
    const int tid = threadIdx.x;
    const int lane = tid & 63;
    const int wid = tid >> 6;                  // 0..7
    const int q31 = lane & 31;
    const int hi = lane >> 5;
    const int rsw = q31 & 7;
    const int b = bh >> 4, h = bh & 15;

    const ushort_t* Q = Qb + (size_t)bh * 2048 * 64;
    const ushort_t* K = Kb + (size_t)bh * 2048 * 64;
    const ushort_t* VT = VTb + (size_t)bh * 64 * 2048;

    __shared__ ushort_t Ksh[3][64 * 64];   // K tile [k][d], chunk-swizzled content
    __shared__ ushort_t Vsh[3][64 * 64];   // V^T tile [d][k], chunk-swizzled content
    __shared__ float Al[8][32];            // per-wave inv-l redistribution (epilogue only)

    const int qw = q0 + wid * 32;

    // Q B-fragments (col=q=lane&31, k-rows d = ds*16 + hi*8 + j) — resident all loop
    s16x8 qf[4];
#pragma unroll
    for (int ds = 0; ds < 4; ++ds)
        qf[ds] = *(const s16x8*)&Q[(size_t)(qw + q31) * 64 + ds * 16 + hi * 8];

    f32x16 o[2] = {};          // O[q-rows][d = db*32 + q31]
    float l_run = 0.f;

    stage_tile(K, VT, Ksh[0], Vsh[0], 0, tid);
    stage_tile(K, VT, Ksh[1], Vsh[1], 64, tid);

    const float negmc = -MFIX * CSC;   // fixed softmax shift (exp2 domain)

    int cur = 0, nx2 = 2;      // buffer of tile t, buffer for tile t+2
    for (int t = 0; t < 32; ++t) {
        // drain tile t's 2 loads; tile t+1's 2 stay in flight across the barrier
        asm volatile("s_waitcnt vmcnt(2)" ::: "memory");
        __builtin_amdgcn_sched_barrier(0);
        __builtin_amdgcn_s_barrier();      // also: all waves done with body t-1 => buf nx2 free
        __builtin_amdgcn_sched_barrier(0);

        int tn = (t + 2 <= 31) ? t + 2 : 31;   // tail: dup-stage keeps vmcnt math uniform
        stage_tile(K, VT, Ksh[nx2], Vsh[nx2], tn * 64, tid);

        const ushort_t* KB = Ksh[cur];
        const ushort_t* VB = Vsh[cur];

        // ---- QK^T: S[k][q], A = K-frag (row k = kb*32 + lane&31), B = Q-frag ----
        f32x16 sa[2];
        sa[0] = (f32x16)0.f; sa[1] = (f32x16)0.f;
        __builtin_amdgcn_s_setprio(1);
#pragma unroll
        for (int kb = 0; kb < 2; ++kb)
#pragma unroll
            for (int ds = 0; ds < 4; ++ds) {
                s16x8 kfr = *(const s16x8*)&KB[(kb * 32 + q31) * 64 + (((2 * ds + hi) ^ rsw) * 8)];
                sa[kb] = __builtin_amdgcn_mfma_f32_32x32x16_bf16(kfr, qf[ds], sa[kb], 0, 0, 0);
            }
        __builtin_amdgcn_s_setprio(0);

        // ---- exp (fixed shift) + sum + pack to PV A-fragments (in-register, T12) ----
        s16x8 pa[4];
        float rs = 0.f;
#pragma unroll
        for (int kb = 0; kb < 2; ++kb) {
            float p[16];
#pragma unroll
            for (int r = 0; r < 16; ++r)
                p[r] = exp2f(fmaf(sa[kb][r], CSC, negmc));
            float s0 = ((p[0] + p[1]) + (p[2] + p[3])) + ((p[4] + p[5]) + (p[6] + p[7]));
            float s1 = ((p[8] + p[9]) + (p[10] + p[11])) + ((p[12] + p[13]) + (p[14] + p[15]));
            rs += s0 + s1;
#pragma unroll
            for (int s = 0; s < 2; ++s) {
                unsigned a0 = cvt_pk_bf16(p[8 * s + 0], p[8 * s + 1]);
                unsigned b0 = cvt_pk_bf16(p[8 * s + 4], p[8 * s + 5]);
                unsigned a1 = cvt_pk_bf16(p[8 * s + 2], p[8 * s + 3]);
                unsigned b1 = cvt_pk_bf16(p[8 * s + 6], p[8 * s + 7]);
                uint2v w02 = pl32swap(a0, b0);   // -> word0, word2
                uint2v w13 = pl32swap(a1, b1);   // -> word1, word3
                union { unsigned u[4]; s16x8 v; } fr;
                fr.u[0] = w02.x; fr.u[1] = w13.x; fr.u[2] = w02.y; fr.u[3] = w13.y;
                pa[kb * 2 + s] = fr.v;
            }
        }
        {
            uint2v w = pl32swap(asu(rs), asu(rs));
            l_run += asf(w.x) + asf(w.y);     // own + partner
        }

        // ---- PV: O[q][d] += P * V, B = V^T-frag (col d = lane&31, k-rows = s*16+hi*8+j) ----
        __builtin_amdgcn_s_setprio(1);
#pragma unroll
        for (int s = 0; s < 4; ++s)
#pragma unroll
            for (int db = 0; db < 2; ++db) {
                s16x8 vfr = *(const s16x8*)&VB[(db * 32 + q31) * 64 + (((2 * s + hi) ^ rsw) * 8)];
                o[db] = __builtin_amdgcn_mfma_f32_32x32x16_bf16(pa[s], vfr, o[db], 0, 0, 0);
            }
        __builtin_amdgcn_s_setprio(0);

        cur = (cur == 2) ? 0 : cur + 1;
        nx2 = (nx2 == 2) ? 0 : nx2 + 1;
    }

    // ---- epilogue: redistribute 1/l to C-layout rows, normalize, store bf16 ----
    Al[wid][q31] = 1.0f / l_run;     // per-wave row: no cross-wave hazard
    __builtin_amdgcn_sched_barrier(0);
    asm volatile("s_waitcnt lgkmcnt(0)" ::: "memory");
#pragma unroll
    for (int g = 0; g < 4; ++g) {
        f32x4 iv = *(const f32x4*)&Al[wid][hi * 4 + g * 8];
#pragma unroll
        for (int j = 0; j < 4; ++j) {
            int qrow = qw + hi * 4 + g * 8 + j;
            size_t base = ((size_t)(b * 2048 + qrow)) * 1024 + h * 64 + q31;
#pragma unroll
            for (int db = 0; db < 2; ++db)
                Ob[base + db * 32] = f2b(o[db][g * 4 + j] * iv[j]);
        }
    }
}

// ---------------- launcher ----------------
extern "C" void kernel_launch(void* const* d_in, const int* in_sizes, int n_in,
                              void* d_out, int out_size, void* d_ws, size_t ws_size,
                              hipStream_t stream) {
    const float* x  = (const float*)d_in[0];
    const float* Wq = (const float*)d_in[1];
    const float* bq = (const float*)d_in[2];
    const float* Wk = (const float*)d_in[3];
    const float* bk = (const float*)d_in[4];
    const float* Wv = (const float*)d_in[5];
    const float* bv = (const float*)d_in[6];
    const float* Wo = (const float*)d_in[7];
    const float* bo = (const float*)d_in[8];
    float* out = (float*)d_out;

    const size_t XN = (size_t)8192 * 1024;
    const size_t WN = (size_t)1024 * 1024;

    ushort_t* Xb  = (ushort_t*)d_ws;
    ushort_t* Wqb = Xb + XN;
    ushort_t* Wkb = Wqb + WN;
    ushort_t* Wvb = Wkb + WN;
    ushort_t* Wob = Wvb + WN;
    ushort_t* Qb  = Wob + WN;
    ushort_t* Kb  = Qb + XN;
    ushort_t* VTb = Kb + XN;   // V transposed: [B,H,64,2048]
    ushort_t* Ob  = VTb + XN;

    cvt_kernel<<<(int)(XN / 4 / 256), 256, 0, stream>>>(x, Xb, (int)XN);
    dim3 gc((int)(WN / 4 / 256), 4);
    cvt4_kernel<<<gc, 256, 0, stream>>>(Wq, Wk, Wv, Wo, Wqb, Wkb, Wvb, Wob);

    dim3 g1(64, 24);
    gemm_qkv<<<g1, 256, 0, stream>>>(Xb, Wqb, Wkb, Wvb, bq, bk, bv, Qb, Kb, VTb);

    attn_kernel<<<512, 512, 0, stream>>>(Qb, Kb, VTb, Ob);

    dim3 g3(64, 8);
    gemm_out<<<g3, 256, 0, stream>>>(Ob, Wob, bo, out);
}

// Round 12
// 225.703 us; speedup vs baseline: 3.0560x; 1.0313x over previous
//
#include <hip/hip_runtime.h>

typedef short s16x8 __attribute__((ext_vector_type(8)));
typedef float f32x4 __attribute__((ext_vector_type(4)));
typedef float f32x16 __attribute__((ext_vector_type(16)));
typedef unsigned uint2v __attribute__((ext_vector_type(2)));
typedef unsigned short ushort_t;

#define CSC 0.18033688011112042f   // 0.125 * log2(e): softmax scale folded into exp2 domain
#define MFIX 16.0f                 // fixed softmax shift: exact (shift-invariant); overflow needs s>700

// fp32 -> bf16 round-to-nearest-even (finite inputs)
__device__ __forceinline__ ushort_t f2b(float f) {
    union { float f; unsigned int u; } c; c.f = f;
    unsigned int u = c.u;
    return (ushort_t)((u + 0x7fffu + ((u >> 16) & 1u)) >> 16);
}

__device__ __forceinline__ unsigned cvt_pk_bf16(float lo, float hi) {
    unsigned r;
    asm("v_cvt_pk_bf16_f32 %0, %1, %2" : "=v"(r) : "v"(lo), "v"(hi));
    return r;
}

__device__ __forceinline__ float asf(unsigned u) { union { unsigned u; float f; } c; c.u = u; return c.f; }
__device__ __forceinline__ unsigned asu(float f) { union { float f; unsigned u; } c; c.f = f; return c.u; }

// swaps a.hi-lanes with b.lo-lanes; for v=v: {x,y} = {own,partner(lane^32)} on every lane
__device__ __forceinline__ uint2v pl32swap(unsigned a, unsigned b) {
#if __has_builtin(__builtin_amdgcn_permlane32_swap)
    return __builtin_amdgcn_permlane32_swap(a, b, false, false);
#else
    asm volatile("v_permlane32_swap_b32 %0, %1" : "+v"(a), "+v"(b));
    uint2v r; r.x = a; r.y = b; return r;
#endif
}

__device__ __forceinline__ void gload_lds16(const void* g, void* lds) {
    __builtin_amdgcn_global_load_lds(
        (const __attribute__((address_space(1))) unsigned int*)g,
        (__attribute__((address_space(3))) unsigned int*)lds, 16, 0, 0);
}

// ---------------- fp32 -> bf16 conversion ----------------
__global__ __launch_bounds__(256) void cvt_kernel(const float* __restrict__ src,
                                                  ushort_t* __restrict__ dst, int n) {
    int i = (blockIdx.x * 256 + threadIdx.x) * 4;
    if (i >= n) return;
    float4 v = *(const float4*)&src[i];
    ushort4 o = make_ushort4(f2b(v.x), f2b(v.y), f2b(v.z), f2b(v.w));
    *(ushort4*)&dst[i] = o;
}

// all four weight matrices in one launch (grid.y selects)
__global__ __launch_bounds__(256) void cvt4_kernel(const float* __restrict__ W0,
                                                   const float* __restrict__ W1,
                                                   const float* __restrict__ W2,
                                                   const float* __restrict__ W3,
                                                   ushort_t* __restrict__ D0,
                                                   ushort_t* __restrict__ D1,
                                                   ushort_t* __restrict__ D2,
                                                   ushort_t* __restrict__ D3) {
    const int w = blockIdx.y;
    const float* src = (w == 0) ? W0 : (w == 1) ? W1 : (w == 2) ? W2 : W3;
    ushort_t* dst = (w == 0) ? D0 : (w == 1) ? D1 : (w == 2) ? D2 : D3;
    int i = (blockIdx.x * 256 + threadIdx.x) * 4;
    float4 v = *(const float4*)&src[i];
    ushort4 o = make_ushort4(f2b(v.x), f2b(v.y), f2b(v.z), f2b(v.w));
    *(ushort4*)&dst[i] = o;
}

// ---------------- GEMM staging: one 128x32 A-tile chunk + B-tile chunk per thread x2 ----------
// Issues 4 global_load_lds per wave per call.
__device__ __forceinline__ void stage_gemm(const ushort_t* __restrict__ A,
                                           const ushort_t* __restrict__ B,
                                           int row0, int tileN, int K, int kt,
                                           ushort_t* As, ushort_t* Bs, int tid) {
#pragma unroll
    for (int i = 0; i < 2; ++i) {
        int c = i * 256 + tid;             // 512 chunks of 16B per 8KB tile
        int r = c >> 2;                    // row 0..127
        int scc = (c & 3) ^ ((r >> 1) & 3);
        gload_lds16(A + (size_t)(row0 + r) * K + kt + scc * 8, As + c * 8);
        gload_lds16(B + (size_t)(tileN + r) * K + kt + scc * 8, Bs + c * 8);
    }
}

// ---------------- shared GEMM main loop: C[128,128] = A[M,K] * B[N,K]^T ----------------
__device__ __forceinline__ void gemm_mainloop(const ushort_t* __restrict__ A,
                                              const ushort_t* __restrict__ B,
                                              int row0, int tileN, int K,
                                              ushort_t* As, ushort_t* Bs,   // 3 buffers, stride 4096 elems
                                              f32x4 acc[4][4]) {
    const int tid = threadIdx.x;
    const int lane = tid & 63;
    const int wid = tid >> 6;
    const int wrow = wid >> 1, wcol = wid & 1;
    const int nT = K >> 5;

    stage_gemm(A, B, row0, tileN, K, 0, As, Bs, tid);
    stage_gemm(A, B, row0, tileN, K, 32, As + 4096, Bs + 4096, tid);

    int cur = 0, nx2 = 2;
    for (int t = 0; t < nT; ++t) {
        // tile t's 4 loads done; tile t+1's 4 stay in flight across the barrier
        asm volatile("s_waitcnt vmcnt(4)" ::: "memory");
        __builtin_amdgcn_sched_barrier(0);
        __builtin_amdgcn_s_barrier();
        __builtin_amdgcn_sched_barrier(0);

        int tn = (t + 2 < nT) ? t + 2 : nT - 1;
        stage_gemm(A, B, row0, tileN, K, tn * 32, As + nx2 * 4096, Bs + nx2 * 4096, tid);

        const ushort_t* Ab = As + cur * 4096;
        const ushort_t* Bb = Bs + cur * 4096;

        s16x8 af[4], bfr[4];
#pragma unroll
        for (int m = 0; m < 4; ++m) {
            int row = wrow * 64 + m * 16 + (lane & 15);
            af[m] = *(const s16x8*)&Ab[row * 32 + (((lane >> 4) ^ ((row >> 1) & 3)) * 8)];
        }
#pragma unroll
        for (int n = 0; n < 4; ++n) {
            int row = wcol * 64 + n * 16 + (lane & 15);
            bfr[n] = *(const s16x8*)&Bb[row * 32 + (((lane >> 4) ^ ((row >> 1) & 3)) * 8)];
        }
#pragma unroll
        for (int m = 0; m < 4; ++m)
#pragma unroll
            for (int n = 0; n < 4; ++n)
                acc[m][n] = __builtin_amdgcn_mfma_f32_16x16x32_bf16(af[m], bfr[n], acc[m][n], 0, 0, 0);

        cur = (cur == 2) ? 0 : cur + 1;
        nx2 = (nx2 == 2) ? 0 : nx2 + 1;
    }
}

// ---------------- QKV projection ----------------
// Q,K scatter to [B,H,N,64] bf16; V written TRANSPOSED to [B,H,64,N] bf16.
// Epilogue bounces the C-tile through the (idle) staging LDS so ALL global stores are
// coalesced 16B chunks (256B per 16-lane group) instead of scattered 2B/8B writes.
__global__ __launch_bounds__(256) void gemm_qkv(const ushort_t* __restrict__ X,
                                                const ushort_t* __restrict__ Wq,
                                                const ushort_t* __restrict__ Wk,
                                                const ushort_t* __restrict__ Wv,
                                                const float* __restrict__ bq,
                                                const float* __restrict__ bk,
                                                const float* __restrict__ bv,
                                                ushort_t* __restrict__ Qb,
                                                ushort_t* __restrict__ Kb,
                                                ushort_t* __restrict__ VTb) {
    __shared__ ushort_t Smem[2 * 3 * 128 * 32];   // staging pool (49152 B); reused as C-tile
    ushort_t* As = Smem;
    ushort_t* Bs = Smem + 3 * 4096;
    const int K = 1024;
    const int tid = threadIdx.x;
    const int lane = tid & 63;
    const int wid = tid >> 6;
    const int wrow = wid >> 1, wcol = wid & 1;
    const int row0 = blockIdx.x * 128;
    const int wsel = blockIdx.y >> 3;
    const int tileN = (blockIdx.y & 7) * 128;
    const ushort_t* B = (wsel == 0) ? Wq : (wsel == 1 ? Wk : Wv);
    const float* bias = (wsel == 0) ? bq : (wsel == 1 ? bk : bv);

    f32x4 acc[4][4] = {};
    gemm_mainloop(X, B, row0, tileN, K, As, Bs, acc);

    // drain in-flight dup-stage DMA, then all waves done with fragment reads -> LDS reusable
    asm volatile("s_waitcnt vmcnt(0)" ::: "memory");
    __syncthreads();

    ushort_t* Ct = Smem;                   // 128 x (128+8) bf16 tile, padded stride 136

    if (wsel == 2) {
        // transpose into LDS: Ct[col][row]; per-lane 4 r-values are row-contiguous -> b64 writes
#pragma unroll
        for (int m = 0; m < 4; ++m)
#pragma unroll
            for (int n = 0; n < 4; ++n) {
                int lrow = wrow * 64 + m * 16 + (lane >> 4) * 4;
                int lcol = wcol * 64 + n * 16 + (lane & 15);
                float bi = bias[tileN + lcol];
                ushort4 w;
                w.x = f2b(acc[m][n][0] + bi);
                w.y = f2b(acc[m][n][1] + bi);
                w.z = f2b(acc[m][n][2] + bi);
                w.w = f2b(acc[m][n][3] + bi);
                *(ushort4*)&Ct[lcol * 136 + lrow] = w;
            }
        __syncthreads();
        // coalesced store: rows of V^T are contiguous along nn
#pragma unroll
        for (int it = 0; it < 8; ++it) {
            int cid = it * 256 + tid;
            int lcol = cid >> 4;           // gcol_local 0..127
            int ch = cid & 15;             // 16B chunk along nn
            int gcol = tileN + lcol;
            int hh = gcol >> 6, hd = gcol & 63;
            int grow = row0 + ch * 8;
            int bb = grow >> 11, nn = grow & 2047;
            uint4 v = *(const uint4*)&Ct[lcol * 136 + ch * 8];
            *(uint4*)&VTb[((size_t)((bb * 16 + hh) * 64 + hd)) * 2048 + nn] = v;
        }
    } else {
        ushort_t* dst = (wsel == 0) ? Qb : Kb;
#pragma unroll
        for (int m = 0; m < 4; ++m)
#pragma unroll
            for (int n = 0; n < 4; ++n) {
                int lrow = wrow * 64 + m * 16 + (lane >> 4) * 4;
                int lcol = wcol * 64 + n * 16 + (lane & 15);
                float bi = bias[tileN + lcol];
#pragma unroll
                for (int r = 0; r < 4; ++r)
                    Ct[(lrow + r) * 136 + lcol] = f2b(acc[m][n][r] + bi);
            }
        __syncthreads();
        // coalesced store: rows of Q/K are contiguous along hd (two 128B head-segments per row)
#pragma unroll
        for (int it = 0; it < 8; ++it) {
            int cid = it * 256 + tid;
            int lrow = cid >> 4;           // 0..127
            int ch = cid & 15;             // 16B chunk along the 128 cols
            int grow = row0 + lrow;
            int gcol = tileN + ch * 8;
            int bb = grow >> 11, nn = grow & 2047;
            int hh = gcol >> 6, hd = gcol & 63;
            uint4 v = *(const uint4*)&Ct[lrow * 136 + ch * 8];
            *(uint4*)&dst[((size_t)((bb * 16 + hh) * 2048 + nn)) * 64 + hd] = v;
        }
    }
}

// ---------------- output projection: fp32 out + bias ----------------
__global__ __launch_bounds__(256) void gemm_out(const ushort_t* __restrict__ A,
                                                const ushort_t* __restrict__ B,
                                                const float* __restrict__ bias,
                                                float* __restrict__ out) {
    __shared__ ushort_t As[3 * 128 * 32];
    __shared__ ushort_t Bs[3 * 128 * 32];
    const int K = 1024;
    const int lane = threadIdx.x & 63;
    const int wid = threadIdx.x >> 6;
    const int wrow = wid >> 1, wcol = wid & 1;
    const int row0 = blockIdx.x * 128;
    const int tileN = blockIdx.y * 128;

    f32x4 acc[4][4] = {};
    gemm_mainloop(A, B, row0, tileN, K, As, Bs, acc);

#pragma unroll
    for (int m = 0; m < 4; ++m)
#pragma unroll
        for (int n = 0; n < 4; ++n)
#pragma unroll
            for (int r = 0; r < 4; ++r) {
                int grow = row0 + wrow * 64 + m * 16 + (lane >> 4) * 4 + r;
                int gcol = tileN + wcol * 64 + n * 16 + (lane & 15);
                out[(size_t)grow * 1024 + gcol] = acc[m][n][r] + bias[gcol];
            }
}

// ---------------- attention staging: K tile + V^T tile, source-side XOR swizzle ----------------
// 512 threads: each thread stages exactly one 16B chunk of K and one of V^T per tile.
__device__ __forceinline__ void stage_tile(const ushort_t* __restrict__ Kg,
                                           const ushort_t* __restrict__ VTg,
                                           ushort_t* KsB, ushort_t* VsB,
                                           int k0, int tid) {
    int r = tid >> 3;                  // row 0..63
    int scc = (tid & 7) ^ (r & 7);     // swizzled 16B-chunk within the row
    gload_lds16(Kg + (size_t)(k0 + r) * 64 + scc * 8, KsB + tid * 8);
    gload_lds16(VTg + (size_t)r * 2048 + k0 + scc * 8, VsB + tid * 8);
}

// ---------------- flash attention fwd (swapped-QK^T 32x32, fixed-shift in-register softmax) ----
// ROUND-11 KERNEL VERBATIM (best measured: 122.9 us).
__global__ __launch_bounds__(512, 4) void attn_kernel(const ushort_t* __restrict__ Qb,
                                                      const ushort_t* __restrict__ Kb,
                                                      const ushort_t* __restrict__ VTb,
                                                      ushort_t* __restrict__ Ob) {
    const int fid = blockIdx.x;
    const int xcd = fid & 7;
    const int slot = fid >> 3;                 // 0..63
    const int qtile = slot & 7;                // 8 q-tiles of 256 rows
    const int bh = (xcd << 3) + (slot >> 3);   // per-XCD K/V working set ~4MB (L2-fit)
    const int q0 = qtile * 256;
    const int tid = threadIdx.x;
    const int lane = tid & 63;
    const int wid = tid >> 6;                  // 0..7
    const int q31 = lane & 31;
    const int hi = lane >> 5;
    const int rsw = q31 & 7;
    const int b = bh >> 4, h = bh & 15;

    const ushort_t* Q = Qb + (size_t)bh * 2048 * 64;
    const ushort_t* K = Kb + (size_t)bh * 2048 * 64;
    const ushort_t* VT = VTb + (size_t)bh * 64 * 2048;

    __shared__ ushort_t Ksh[3][64 * 64];   // K tile [k][d], chunk-swizzled content
    __shared__ ushort_t Vsh[3][64 * 64];   // V^T tile [d][k], chunk-swizzled content
    __shared__ float Al[8][32];            // per-wave inv-l redistribution (epilogue only)

    const int qw = q0 + wid * 32;

    // Q B-fragments (col=q=lane&31, k-rows d = ds*16 + hi*8 + j) — resident all loop
    s16x8 qf[4];
#pragma unroll
    for (int ds = 0; ds < 4; ++ds)
        qf[ds] = *(const s16x8*)&Q[(size_t)(qw + q31) * 64 + ds * 16 + hi * 8];

    f32x16 o[2] = {};          // O[q-rows][d = db*32 + q31]
    float l_run = 0.f;

    stage_tile(K, VT, Ksh[0], Vsh[0], 0, tid);
    stage_tile(K, VT, Ksh[1], Vsh[1], 64, tid);

    const float negmc = -MFIX * CSC;   // fixed softmax shift (exp2 domain)

    int cur = 0, nx2 = 2;      // buffer of tile t, buffer for tile t+2
    for (int t = 0; t < 32; ++t) {
        // drain tile t's 2 loads; tile t+1's 2 stay in flight across the barrier
        asm volatile("s_waitcnt vmcnt(2)" ::: "memory");
        __builtin_amdgcn_sched_barrier(0);
        __builtin_amdgcn_s_barrier();      // also: all waves done with body t-1 => buf nx2 free
        __builtin_amdgcn_sched_barrier(0);

        int tn = (t + 2 <= 31) ? t + 2 : 31;   // tail: dup-stage keeps vmcnt math uniform
        stage_tile(K, VT, Ksh[nx2], Vsh[nx2], tn * 64, tid);

        const ushort_t* KB = Ksh[cur];
        const ushort_t* VB = Vsh[cur];

        // ---- QK^T: S[k][q], A = K-frag (row k = kb*32 + lane&31), B = Q-frag ----
        f32x16 sa[2];
        sa[0] = (f32x16)0.f; sa[1] = (f32x16)0.f;
        __builtin_amdgcn_s_setprio(1);
#pragma unroll
        for (int kb = 0; kb < 2; ++kb)
#pragma unroll
            for (int ds = 0; ds < 4; ++ds) {
                s16x8 kfr = *(const s16x8*)&KB[(kb * 32 + q31) * 64 + (((2 * ds + hi) ^ rsw) * 8)];
                sa[kb] = __builtin_amdgcn_mfma_f32_32x32x16_bf16(kfr, qf[ds], sa[kb], 0, 0, 0);
            }
        __builtin_amdgcn_s_setprio(0);

        // ---- exp (fixed shift) + sum + pack to PV A-fragments (in-register, T12) ----
        s16x8 pa[4];
        float rs = 0.f;
#pragma unroll
        for (int kb = 0; kb < 2; ++kb) {
            float p[16];
#pragma unroll
            for (int r = 0; r < 16; ++r)
                p[r] = exp2f(fmaf(sa[kb][r], CSC, negmc));
            float s0 = ((p[0] + p[1]) + (p[2] + p[3])) + ((p[4] + p[5]) + (p[6] + p[7]));
            float s1 = ((p[8] + p[9]) + (p[10] + p[11])) + ((p[12] + p[13]) + (p[14] + p[15]));
            rs += s0 + s1;
#pragma unroll
            for (int s = 0; s < 2; ++s) {
                unsigned a0 = cvt_pk_bf16(p[8 * s + 0], p[8 * s + 1]);
                unsigned b0 = cvt_pk_bf16(p[8 * s + 4], p[8 * s + 5]);
                unsigned a1 = cvt_pk_bf16(p[8 * s + 2], p[8 * s + 3]);
                unsigned b1 = cvt_pk_bf16(p[8 * s + 6], p[8 * s + 7]);
                uint2v w02 = pl32swap(a0, b0);   // -> word0, word2
                uint2v w13 = pl32swap(a1, b1);   // -> word1, word3
                union { unsigned u[4]; s16x8 v; } fr;
                fr.u[0] = w02.x; fr.u[1] = w13.x; fr.u[2] = w02.y; fr.u[3] = w13.y;
                pa[kb * 2 + s] = fr.v;
            }
        }
        {
            uint2v w = pl32swap(asu(rs), asu(rs));
            l_run += asf(w.x) + asf(w.y);     // own + partner
        }

        // ---- PV: O[q][d] += P * V, B = V^T-frag (col d = lane&31, k-rows = s*16+hi*8+j) ----
        __builtin_amdgcn_s_setprio(1);
#pragma unroll
        for (int s = 0; s < 4; ++s)
#pragma unroll
            for (int db = 0; db < 2; ++db) {
                s16x8 vfr = *(const s16x8*)&VB[(db * 32 + q31) * 64 + (((2 * s + hi) ^ rsw) * 8)];
                o[db] = __builtin_amdgcn_mfma_f32_32x32x16_bf16(pa[s], vfr, o[db], 0, 0, 0);
            }
        __builtin_amdgcn_s_setprio(0);

        cur = (cur == 2) ? 0 : cur + 1;
        nx2 = (nx2 == 2) ? 0 : nx2 + 1;
    }

    // ---- epilogue: redistribute 1/l to C-layout rows, normalize, store bf16 ----
    Al[wid][q31] = 1.0f / l_run;     // per-wave row: no cross-wave hazard
    __builtin_amdgcn_sched_barrier(0);
    asm volatile("s_waitcnt lgkmcnt(0)" ::: "memory");
#pragma unroll
    for (int g = 0; g < 4; ++g) {
        f32x4 iv = *(const f32x4*)&Al[wid][hi * 4 + g * 8];
#pragma unroll
        for (int j = 0; j < 4; ++j) {
            int qrow = qw + hi * 4 + g * 8 + j;
            size_t base = ((size_t)(b * 2048 + qrow)) * 1024 + h * 64 + q31;
#pragma unroll
            for (int db = 0; db < 2; ++db)
                Ob[base + db * 32] = f2b(o[db][g * 4 + j] * iv[j]);
        }
    }
}

// ---------------- launcher ----------------
extern "C" void kernel_launch(void* const* d_in, const int* in_sizes, int n_in,
                              void* d_out, int out_size, void* d_ws, size_t ws_size,
                              hipStream_t stream) {
    const float* x  = (const float*)d_in[0];
    const float* Wq = (const float*)d_in[1];
    const float* bq = (const float*)d_in[2];
    const float* Wk = (const float*)d_in[3];
    const float* bk = (const float*)d_in[4];
    const float* Wv = (const float*)d_in[5];
    const float* bv = (const float*)d_in[6];
    const float* Wo = (const float*)d_in[7];
    const float* bo = (const float*)d_in[8];
    float* out = (float*)d_out;

    const size_t XN = (size_t)8192 * 1024;
    const size_t WN = (size_t)1024 * 1024;

    ushort_t* Xb  = (ushort_t*)d_ws;
    ushort_t* Wqb = Xb + XN;
    ushort_t* Wkb = Wqb + WN;
    ushort_t* Wvb = Wkb + WN;
    ushort_t* Wob = Wvb + WN;
    ushort_t* Qb  = Wob + WN;
    ushort_t* Kb  = Qb + XN;
    ushort_t* VTb = Kb + XN;   // V transposed: [B,H,64,2048]
    ushort_t* Ob  = VTb + XN;

    cvt_kernel<<<(int)(XN / 4 / 256), 256, 0, stream>>>(x, Xb, (int)XN);
    dim3 gc((int)(WN / 4 / 256), 4);
    cvt4_kernel<<<gc, 256, 0, stream>>>(Wq, Wk, Wv, Wo, Wqb, Wkb, Wvb, Wob);

    dim3 g1(64, 24);
    gemm_qkv<<<g1, 256, 0, stream>>>(Xb, Wqb, Wkb, Wvb, bq, bk, bv, Qb, Kb, VTb);

    attn_kernel<<<512, 512, 0, stream>>>(Qb, Kb, VTb, Ob);

    dim3 g3(64, 8);
    gemm_out<<<g3, 256, 0, stream>>>(Ob, Wob, bo, out);
}